// Round 4
// baseline (443.804 us; speedup 1.0000x reference)
//
#include <hip/hip_runtime.h>
#include <hip/hip_bf16.h>
#include <float.h>
#include <math.h>

#define N_TOK 16384
#define DIM   2048
#define NE    64
#define NR    128        // 64 gate + 64 noise expert-rows
#define EPSF  1e-9f

typedef short short8v __attribute__((ext_vector_type(8)));   // 8 bf16 (4 VGPR)
typedef float float4v __attribute__((ext_vector_type(4)));   // MFMA C/D frag

// ---------- bf16 limb helpers ----------
__device__ __forceinline__ float bfround(float f) {          // RNE to bf16, kept in f32
    unsigned u = __float_as_uint(f);
    u = (u + 0x7FFFu + ((u >> 16) & 1u)) & 0xFFFF0000u;
    return __uint_as_float(u);
}
__device__ __forceinline__ unsigned short bftop(float f) {   // bf16 bits of rounded value
    return (unsigned short)(__float_as_uint(f) >> 16);
}

// ---------- wave helpers (wave64) ----------
__device__ __forceinline__ float wave_sum(float v) {
#pragma unroll
    for (int d = 32; d > 0; d >>= 1) v += __shfl_xor(v, d, 64);
    return v;
}
__device__ __forceinline__ void wave_argmax(float v, int i, float& mv, int& mi) {
    float bv = v; int bi = i;
#pragma unroll
    for (int d = 32; d > 0; d >>= 1) {
        float ov = __shfl_xor(bv, d, 64);
        int   oi = __shfl_xor(bi, d, 64);
        if (ov > bv || (ov == bv && oi < bi)) { bv = ov; bi = oi; }
    }
    mv = bv; mi = bi;
}

// ---------- pre-kernel: W -> 3 bf16 limbs, [limb][row][k] ----------
__global__ __launch_bounds__(256) void wlimb_kernel(
    const float* __restrict__ Wg, const float* __restrict__ Wn,
    unsigned short* __restrict__ W3)
{
    int idx = blockIdx.x * 256 + threadIdx.x;     // 0 .. 262143
    int row = idx >> 11, k = idx & 2047;
    float wv = (row < NE) ? Wg[row * 2048 + k] : Wn[(row - NE) * 2048 + k];
    float h = bfround(wv);
    float r = wv - h;
    float m = bfround(r);
    float l = bfround(r - m);
    W3[idx]          = bftop(h);
    W3[262144 + idx] = bftop(m);
    W3[524288 + idx] = bftop(l);
}

// ---------- 6-product bf16-limb MFMA GEMM: logits = x @ [Wg;Wn]^T ----------
// grid = 768: wg = p*128 + tile  (tile 0..127 => 128 tokens each; p 0..5 = limb product)
// block = 128 thr (2 waves); wave = 64 tok x 128 rows as 4x8 tiles of 16x16x32
__global__ __launch_bounds__(128, 1) void mfma6_kernel(
    const float* __restrict__ x,            // [N_TOK][DIM] f32
    const unsigned short* __restrict__ W3,  // [3][NR][DIM] bf16 limbs
    float* __restrict__ P)                  // [N_TOK][NR] f32, pre-zeroed (atomic accum)
{
    __shared__ unsigned char lx[128 * 128];  // 128 tok x 64 k bf16, XOR-swizzled rows

    const int wg   = blockIdx.x;
    const int tile = wg & 127;
    const int p    = wg >> 7;
    // product p -> (x limb, W limb): hh, hm, mh, hl, mm, lh
    const int a_sel = (p == 2 || p == 4) ? 1 : (p == 5 ? 2 : 0);
    const int b_sel = (p == 1 || p == 4) ? 1 : (p == 3 ? 2 : 0);

    const int t    = threadIdx.x;
    const int w    = t >> 6;
    const int lane = t & 63;
    const int l15  = lane & 15, l4 = lane >> 4;
    const int tokBase = tile * 128;

    float4v acc[4][8];
#pragma unroll
    for (int mi = 0; mi < 4; ++mi)
#pragma unroll
        for (int ni = 0; ni < 8; ++ni)
            acc[mi][ni] = (float4v){0.f, 0.f, 0.f, 0.f};

    const unsigned short* Wb = W3 + (size_t)b_sel * (NR * DIM);

    for (int kt = 0; kt < 32; ++kt) {
        const int k0 = kt * 64;
        __syncthreads();                       // prior-iter LDS reads done
        // ---- stage x-limb tile [128 tok][64 k]: 16 float4 per thread ----
        float4v v[16];
#pragma unroll
        for (int i = 0; i < 16; ++i) {
            int idx = t + 128 * i;             // 0..2047
            int tok = idx >> 4, k4 = idx & 15;
            v[i] = *(const float4v*)(x + (size_t)(tokBase + tok) * DIM + k0 + k4 * 4);
        }
#pragma unroll
        for (int i = 0; i < 16; ++i) {
            int idx = t + 128 * i;
            int tok = idx >> 4, k4 = idx & 15;
            unsigned long long pk = 0ull;
#pragma unroll
            for (int c = 0; c < 4; ++c) {
                float xv = v[i][c];
                float h = bfround(xv);
                float r = xv - h;
                float m = bfround(r);
                float l = bfround(r - m);
                float pick = (a_sel == 0) ? h : ((a_sel == 1) ? m : l);
                pk |= (unsigned long long)bftop(pick) << (16 * c);
            }
            int boff = tok * 128 + ((k4 * 8) ^ ((tok & 7) << 4));  // XOR-swizzle
            *(unsigned long long*)(lx + boff) = pk;
        }
        __syncthreads();

        // ---- B fragments straight from L2 (W3 is 1.5 MB, resident) ----
        short8v pb[2][8];
#pragma unroll
        for (int kk2 = 0; kk2 < 2; ++kk2)
#pragma unroll
            for (int ni = 0; ni < 8; ++ni)
                pb[kk2][ni] = *(const short8v*)(Wb + (size_t)(ni * 16 + l15) * DIM
                                                   + k0 + kk2 * 32 + l4 * 8);
        // ---- 2 k-steps x 32 MFMA ----
#pragma unroll
        for (int kk2 = 0; kk2 < 2; ++kk2) {
            short8v af[4];
#pragma unroll
            for (int mi = 0; mi < 4; ++mi) {
                int tok = w * 64 + mi * 16 + l15;
                int boff = tok * 128 + ((kk2 * 64 + l4 * 16) ^ ((tok & 7) << 4));
                af[mi] = *(const short8v*)(lx + boff);
            }
#pragma unroll
            for (int mi = 0; mi < 4; ++mi)
#pragma unroll
                for (int ni = 0; ni < 8; ++ni)
                    acc[mi][ni] = __builtin_amdgcn_mfma_f32_16x16x32_bf16(
                        af[mi], pb[kk2][ni], acc[mi][ni], 0, 0, 0);
        }
    }

    // ---- combine the 6 products: fp32 atomics into P ----
    // D frag: col(e) = lane&15, row(tok) = (lane>>4)*4 + r
#pragma unroll
    for (int mi = 0; mi < 4; ++mi)
#pragma unroll
        for (int ni = 0; ni < 8; ++ni)
#pragma unroll
            for (int r = 0; r < 4; ++r) {
                int tok = tokBase + w * 64 + mi * 16 + l4 * 4 + r;
                int e   = ni * 16 + l15;
                atomicAdd(&P[(size_t)tok * NR + e], acc[mi][ni][r]);
            }
}

// ---------- epilogue: router math, 32 tokens/block ----------
__global__ __launch_bounds__(256) void epilogue_kernel(
    const float* __restrict__ P,      // [N_TOK][NR] summed logits
    const float* __restrict__ noise,  // [N_TOK][NE]
    float* __restrict__ out,          // topi(2N) | weights(2N) | priority(N) | aux(1)
    float* __restrict__ accum)        // importance[64] | load[64]
{
    __shared__ float s_part[4][2][NE];
    const int t    = threadIdx.x;
    const int wv   = t >> 6;
    const int lane = t & 63;

    float imp_acc = 0.f, load_acc = 0.f;

    for (int s = 0; s < 8; ++s) {
        const int tok = blockIdx.x * 32 + wv * 8 + s;

        float logit = P[(size_t)tok * NR + lane];
        float rawn  = P[(size_t)tok * NR + 64 + lane];
        float sp    = fmaxf(rawn, 0.f) + log1pf(expf(-fabsf(rawn)));
        float nstd  = sp + EPSF;
        float nz    = noise[(size_t)tok * NE + lane];
        float noisy = logit + nz * nstd;

        float v0, v1, v2; int i0, i1, i2d;
        wave_argmax(noisy, lane, v0, i0);
        float m1 = (lane == i0) ? -FLT_MAX : noisy;
        wave_argmax(m1, lane, v1, i1);
        float m2 = (lane == i0 || lane == i1) ? -FLT_MAX : noisy;
        wave_argmax(m2, lane, v2, i2d);
        (void)i2d;

        float e1  = expf(v1 - v0);
        float den = 1.f + e1;
        float w0v = 1.f / den;
        float w1v = e1 / den;

        if (lane == 0) {
            out[2 * tok]                 = (float)i0;
            out[2 * tok + 1]             = (float)i1;
            out[2 * N_TOK + 2 * tok]     = w0v;
            out[2 * N_TOK + 2 * tok + 1] = w1v;
            out[4 * N_TOK + tok]         = w0v;
        }

        imp_acc += (lane == i0) ? w0v : ((lane == i1) ? w1v : 0.f);

        bool in_topk = (lane == i0) || (lane == i1);
        float kth = in_topk ? v2 : v1;
        float z = (logit - kth) / (nstd + EPSF);
        load_acc += 0.5f * (1.f + erff(z * 0.7071067811865476f));
    }

    s_part[wv][0][lane] = imp_acc;
    s_part[wv][1][lane] = load_acc;
    __syncthreads();

    if (t < 2 * NE) {
        int which = t >> 6, e = t & 63;
        float s = s_part[0][which][e] + s_part[1][which][e]
                + s_part[2][which][e] + s_part[3][which][e];
        atomicAdd(&accum[which * NE + e], s);
    }
}

// ---------- finalize ----------
__global__ void finalize_kernel(const float* __restrict__ accum,
                                float* __restrict__ out_aux) {
    const int lane = threadIdx.x;
    float imp  = accum[lane];
    float load = accum[NE + lane];

    float m_imp = wave_sum(imp) * (1.f / NE);
    float di = imp - m_imp;
    float var_imp = wave_sum(di * di) * (1.f / NE);

    float m_load = wave_sum(load) * (1.f / NE);
    float dl = load - m_load;
    float var_load = wave_sum(dl * dl) * (1.f / NE);

    if (lane == 0) {
        out_aux[0] = 0.1f * (var_imp  / (m_imp  * m_imp  + EPSF))
                   + 0.1f * (var_load / (m_load * m_load + EPSF));
    }
}

extern "C" void kernel_launch(void* const* d_in, const int* in_sizes, int n_in,
                              void* d_out, int out_size, void* d_ws, size_t ws_size,
                              hipStream_t stream) {
    const float* x     = (const float*)d_in[0];
    const float* noise = (const float*)d_in[1];
    const float* Wg    = (const float*)d_in[2];
    const float* Wn    = (const float*)d_in[3];
    float* out = (float*)d_out;

    float*          accum = (float*)d_ws;                                   // 512 B
    unsigned short* W3    = (unsigned short*)((char*)d_ws + 1024);          // 1.5 MB
    float*          P     = (float*)((char*)d_ws + (2u << 20));             // 8.4 MB

    hipMemsetAsync(accum, 0, 2 * NE * sizeof(float), stream);
    hipMemsetAsync(P, 0, (size_t)N_TOK * NR * sizeof(float), stream);
    wlimb_kernel<<<1024, 256, 0, stream>>>(Wg, Wn, W3);
    mfma6_kernel<<<768, 128, 0, stream>>>(x, W3, P);
    epilogue_kernel<<<N_TOK / 32, 256, 0, stream>>>(P, noise, out, accum);
    finalize_kernel<<<1, 64, 0, stream>>>(accum, out + 5 * (size_t)N_TOK);
}

// Round 5
// 321.948 us; speedup vs baseline: 1.3785x; 1.3785x over previous
//
#include <hip/hip_runtime.h>
#include <hip/hip_bf16.h>
#include <float.h>
#include <math.h>

#define N_TOK 16384
#define DIM   2048
#define NE    64
#define NR    128        // 64 gate + 64 noise expert-rows
#define KT    64         // K per staging tile
#define NKT   32         // DIM/KT
#define EPSF  1e-9f

typedef short short8v __attribute__((ext_vector_type(8)));   // 8 bf16 (4 VGPR)
typedef float float4v __attribute__((ext_vector_type(4)));   // MFMA C/D frag

// ---------- bf16 limb helpers ----------
__device__ __forceinline__ float bfround(float f) {          // RNE to bf16, kept in f32
    unsigned u = __float_as_uint(f);
    u = (u + 0x7FFFu + ((u >> 16) & 1u)) & 0xFFFF0000u;
    return __uint_as_float(u);
}
__device__ __forceinline__ unsigned short bftop(float f) {
    return (unsigned short)(__float_as_uint(f) >> 16);
}

// ---------- wave helpers (wave64) ----------
__device__ __forceinline__ float wave_sum(float v) {
#pragma unroll
    for (int d = 32; d > 0; d >>= 1) v += __shfl_xor(v, d, 64);
    return v;
}
__device__ __forceinline__ void wave_argmax(float v, int i, float& mv, int& mi) {
    float bv = v; int bi = i;
#pragma unroll
    for (int d = 32; d > 0; d >>= 1) {
        float ov = __shfl_xor(bv, d, 64);
        int   oi = __shfl_xor(bi, d, 64);
        if (ov > bv || (ov == bv && oi < bi)) { bv = ov; bi = oi; }
    }
    mv = bv; mi = bi;
}

// ---------- prep: W -> 3 bf16 limbs [limb][row][k]; zero accum + ticket ----------
__global__ __launch_bounds__(256) void prep_kernel(
    const float* __restrict__ Wg, const float* __restrict__ Wn,
    unsigned short* __restrict__ W3, float* __restrict__ accum,
    unsigned* __restrict__ counter)
{
    if (blockIdx.x == 0) {
        if (threadIdx.x < 128) accum[threadIdx.x] = 0.f;
        if (threadIdx.x == 128) *counter = 0u;
    }
    int idx = blockIdx.x * 256 + threadIdx.x;     // 0 .. 262143
    int row = idx >> 11, k = idx & 2047;
    float wv = (row < NE) ? Wg[row * 2048 + k] : Wn[(row - NE) * 2048 + k];
    float h = bfround(wv);
    float r = wv - h;
    float m = bfround(r);
    float l = bfround(r - m);
    W3[idx]          = bftop(h);
    W3[262144 + idx] = bftop(m);
    W3[524288 + idx] = bftop(l);
}

// ---------- 6-product bf16-limb MFMA GEMM, all products per block ----------
// grid 512: swizzled -> (token-tile 0..255, half 0/1); block 256 thr = 4 waves (2x2)
__global__ __launch_bounds__(256, 2) void gemm6_kernel(
    const float* __restrict__ x,            // [N_TOK][DIM]
    const unsigned short* __restrict__ W3,  // [3][NR][DIM] bf16 limbs
    float* __restrict__ P)                  // [N_TOK][NR] logits
{
    __shared__ __align__(16) unsigned char lx[3 * 64 * 128];  // 3 limb planes, 64 tok x 128B

    // bijective XCD swizzle: pair (tile,half=0/1) lands on same XCD (same orig%8)
    const int orig = blockIdx.x;
    const int L    = (orig & 7) * 64 + (orig >> 3);
    const int tile = L >> 1;
    const int half = L & 1;
    const int tokBase = tile * 64;
    const int rowBase = half * 64;

    const int t    = threadIdx.x;
    const int w    = t >> 6;
    const int wr   = w >> 1, wc = w & 1;    // wave tile: 32 tok x 32 rows
    const int lane = t & 63;
    const int l15  = lane & 15, l4 = lane >> 4;

    // staging mapping: idx = t + 256*i -> tok (t>>3)+32i, k-group t&7 (8 floats each)
    const int stok = t >> 3;
    const int skg  = t & 7;

    float4v acc[6][2][2];
#pragma unroll
    for (int p = 0; p < 6; ++p)
#pragma unroll
        for (int mi = 0; mi < 2; ++mi)
#pragma unroll
            for (int ni = 0; ni < 2; ++ni)
                acc[p][mi][ni] = (float4v){0.f, 0.f, 0.f, 0.f};

    // prefetch x for kt=0
    float4v px[2][2];
#pragma unroll
    for (int i = 0; i < 2; ++i) {
        const float* src = x + (size_t)(tokBase + stok + 32 * i) * DIM + skg * 8;
        px[i][0] = *(const float4v*)src;
        px[i][1] = *(const float4v*)(src + 4);
    }

    for (int kt = 0; kt < NKT; ++kt) {
        const int k0 = kt * KT;
        // B-limb fragments straight from L2 (W3 resident, 1.5 MB)
        short8v bf[2][3][2];
#pragma unroll
        for (int kk2 = 0; kk2 < 2; ++kk2)
#pragma unroll
            for (int lb = 0; lb < 3; ++lb)
#pragma unroll
                for (int ni = 0; ni < 2; ++ni)
                    bf[kk2][lb][ni] = *(const short8v*)(W3 + (size_t)lb * (NR * DIM)
                        + (size_t)(rowBase + wc * 32 + ni * 16 + l15) * DIM
                        + k0 + kk2 * 32 + l4 * 8);

        __syncthreads();   // prior iteration's LDS reads complete
        // decompose prefetched x -> 3 limb planes (XOR-swizzled rows)
#pragma unroll
        for (int i = 0; i < 2; ++i) {
            const int tok = stok + 32 * i;
            short8v sh, sm, sl;
#pragma unroll
            for (int c = 0; c < 8; ++c) {
                float f = (c < 4) ? px[i][0][c] : px[i][1][c - 4];
                float h = bfround(f);
                float r = f - h;
                float m = bfround(r);
                float l = bfround(r - m);
                sh[c] = (short)bftop(h);
                sm[c] = (short)bftop(m);
                sl[c] = (short)bftop(l);
            }
            const int boff = tok * 128 + ((skg * 16) ^ ((tok & 7) << 4));
            *(short8v*)(lx + boff)         = sh;
            *(short8v*)(lx + 8192 + boff)  = sm;
            *(short8v*)(lx + 16384 + boff) = sl;
        }
        __syncthreads();

        // prefetch next x tile (overlaps MFMA below)
        if (kt + 1 < NKT) {
#pragma unroll
            for (int i = 0; i < 2; ++i) {
                const float* src = x + (size_t)(tokBase + stok + 32 * i) * DIM
                                     + k0 + KT + skg * 8;
                px[i][0] = *(const float4v*)src;
                px[i][1] = *(const float4v*)(src + 4);
            }
        }

#pragma unroll
        for (int kk2 = 0; kk2 < 2; ++kk2) {
            short8v af[3][2];
#pragma unroll
            for (int lb = 0; lb < 3; ++lb)
#pragma unroll
                for (int mi = 0; mi < 2; ++mi) {
                    const int tokl = wr * 32 + mi * 16 + l15;
                    const int boff = tokl * 128
                        + ((kk2 * 64 + l4 * 16) ^ ((tokl & 7) << 4));
                    af[lb][mi] = *(const short8v*)(lx + lb * 8192 + boff);
                }
#pragma unroll
            for (int mi = 0; mi < 2; ++mi)
#pragma unroll
                for (int ni = 0; ni < 2; ++ni) {
                    acc[0][mi][ni] = __builtin_amdgcn_mfma_f32_16x16x32_bf16(af[0][mi], bf[kk2][0][ni], acc[0][mi][ni], 0, 0, 0); // hh
                    acc[1][mi][ni] = __builtin_amdgcn_mfma_f32_16x16x32_bf16(af[0][mi], bf[kk2][1][ni], acc[1][mi][ni], 0, 0, 0); // hm
                    acc[2][mi][ni] = __builtin_amdgcn_mfma_f32_16x16x32_bf16(af[1][mi], bf[kk2][0][ni], acc[2][mi][ni], 0, 0, 0); // mh
                    acc[3][mi][ni] = __builtin_amdgcn_mfma_f32_16x16x32_bf16(af[0][mi], bf[kk2][2][ni], acc[3][mi][ni], 0, 0, 0); // hl
                    acc[4][mi][ni] = __builtin_amdgcn_mfma_f32_16x16x32_bf16(af[1][mi], bf[kk2][1][ni], acc[4][mi][ni], 0, 0, 0); // mm
                    acc[5][mi][ni] = __builtin_amdgcn_mfma_f32_16x16x32_bf16(af[2][mi], bf[kk2][0][ni], acc[5][mi][ni], 0, 0, 0); // lh
                }
        }
    }

    // sum the 6 products, store logits (D frag: col=l15, row=l4*4+r)
#pragma unroll
    for (int mi = 0; mi < 2; ++mi)
#pragma unroll
        for (int ni = 0; ni < 2; ++ni)
#pragma unroll
            for (int r = 0; r < 4; ++r) {
                float v = acc[0][mi][ni][r] + acc[1][mi][ni][r] + acc[2][mi][ni][r]
                        + acc[3][mi][ni][r] + acc[4][mi][ni][r] + acc[5][mi][ni][r];
                const int tok = tokBase + wr * 32 + mi * 16 + l4 * 4 + r;
                const int row = rowBase + wc * 32 + ni * 16 + l15;
                P[(size_t)tok * NR + row] = v;
            }
}

// ---------- epilogue: router math + fused finalize (last-block ticket) ----------
__global__ __launch_bounds__(256) void epilogue_kernel(
    const float* __restrict__ P,      // [N_TOK][NR]
    const float* __restrict__ noise,  // [N_TOK][NE]
    float* __restrict__ out,          // topi(2N) | weights(2N) | priority(N) | aux(1)
    float* __restrict__ accum,        // importance[64] | load[64]
    unsigned* __restrict__ counter)
{
    __shared__ float s_part[4][2][NE];
    __shared__ int is_last;
    const int t    = threadIdx.x;
    const int wv   = t >> 6;
    const int lane = t & 63;

    float imp_acc = 0.f, load_acc = 0.f;

    for (int s = 0; s < 8; ++s) {
        const int tok = blockIdx.x * 32 + wv * 8 + s;

        float logit = P[(size_t)tok * NR + lane];
        float rawn  = P[(size_t)tok * NR + 64 + lane];
        float sp    = fmaxf(rawn, 0.f) + log1pf(expf(-fabsf(rawn)));
        float nstd  = sp + EPSF;
        float nz    = noise[(size_t)tok * NE + lane];
        float noisy = logit + nz * nstd;

        float v0, v1, v2; int i0, i1, i2d;
        wave_argmax(noisy, lane, v0, i0);
        float m1 = (lane == i0) ? -FLT_MAX : noisy;
        wave_argmax(m1, lane, v1, i1);
        float m2 = (lane == i0 || lane == i1) ? -FLT_MAX : noisy;
        wave_argmax(m2, lane, v2, i2d);
        (void)i2d;

        float e1  = expf(v1 - v0);
        float den = 1.f + e1;
        float w0v = 1.f / den;
        float w1v = e1 / den;

        if (lane == 0) {
            out[2 * tok]                 = (float)i0;
            out[2 * tok + 1]             = (float)i1;
            out[2 * N_TOK + 2 * tok]     = w0v;
            out[2 * N_TOK + 2 * tok + 1] = w1v;
            out[4 * N_TOK + tok]         = w0v;
        }

        imp_acc += (lane == i0) ? w0v : ((lane == i1) ? w1v : 0.f);

        bool in_topk = (lane == i0) || (lane == i1);
        float kth = in_topk ? v2 : v1;
        float z = (logit - kth) / (nstd + EPSF);
        load_acc += 0.5f * (1.f + erff(z * 0.7071067811865476f));
    }

    s_part[wv][0][lane] = imp_acc;
    s_part[wv][1][lane] = load_acc;
    __syncthreads();

    if (t < 2 * NE) {
        int which = t >> 6, e = t & 63;
        float s = s_part[0][which][e] + s_part[1][which][e]
                + s_part[2][which][e] + s_part[3][which][e];
        atomicAdd(&accum[which * NE + e], s);
    }
    __threadfence();
    __syncthreads();
    if (t == 0) {
        unsigned done = atomicAdd(counter, 1u);
        is_last = (done == gridDim.x - 1) ? 1 : 0;
    }
    __syncthreads();

    if (is_last && t < NE) {
        __threadfence();
        float imp  = atomicAdd(&accum[t], 0.f);        // device-coherent read
        float load = atomicAdd(&accum[NE + t], 0.f);

        float m_imp = wave_sum(imp) * (1.f / NE);
        float di = imp - m_imp;
        float var_imp = wave_sum(di * di) * (1.f / NE);

        float m_load = wave_sum(load) * (1.f / NE);
        float dl = load - m_load;
        float var_load = wave_sum(dl * dl) * (1.f / NE);

        if (t == 0) {
            out[5 * (size_t)N_TOK] = 0.1f * (var_imp  / (m_imp  * m_imp  + EPSF))
                                   + 0.1f * (var_load / (m_load * m_load + EPSF));
        }
    }
}

extern "C" void kernel_launch(void* const* d_in, const int* in_sizes, int n_in,
                              void* d_out, int out_size, void* d_ws, size_t ws_size,
                              hipStream_t stream) {
    const float* x     = (const float*)d_in[0];
    const float* noise = (const float*)d_in[1];
    const float* Wg    = (const float*)d_in[2];
    const float* Wn    = (const float*)d_in[3];
    float* out = (float*)d_out;

    float*          accum   = (float*)d_ws;                            // 128 f32
    unsigned*       counter = (unsigned*)((char*)d_ws + 512);          // ticket
    unsigned short* W3      = (unsigned short*)((char*)d_ws + 1024);   // 1.5 MB
    float*          P       = (float*)((char*)d_ws + (2u << 20));      // 8.4 MB

    prep_kernel<<<1024, 256, 0, stream>>>(Wg, Wn, W3, accum, counter);
    gemm6_kernel<<<512, 256, 0, stream>>>(x, W3, P);
    epilogue_kernel<<<N_TOK / 32, 256, 0, stream>>>(P, noise, out, accum, counter);
}